// Round 5
// baseline (2420.454 us; speedup 1.0000x reference)
//
#include <hip/hip_runtime.h>

// ---------------------------------------------------------------------------
// HeadsSelection: emb-gather -> 2x bidirectional LSTM -> additive attention
// S=256, B=16, V=20000, E=512, H=256, L=2, HM=128
// Round 5: fewer/bigger recurrence WGs + coalesced Gin.
//   - k_lstm: 8 WGs (4/dir) x 1024 thr (16 waves; wave = one 16x16 MFMA tile).
//     Stage = 4 u64 loads/lane (was 16) -> shorter vmcnt drain per retry.
//     Same stamp-in-u64 single-round-trip exchange (R4), same split-bf16
//     3-product MFMA (fp32-class accuracy).
//   - G in row-major [m][2048]: GEMM store + per-step Gin reads coalesced.
//   - k_attn: hardware-exp tanh (v_exp_f32) instead of libm tanhf.
// ---------------------------------------------------------------------------

#define S_    256
#define B_    16
#define E_    512
#define H_    256
#define HM_   128
#define M_    4096   // S*B

typedef __attribute__((ext_vector_type(8))) short short8;
typedef __attribute__((ext_vector_type(4))) float f32x4;

__device__ __forceinline__ float sigm(float x) { return 1.f / (1.f + __expf(-x)); }
__device__ __forceinline__ float tanh_fast(float x) {
  x = fminf(fmaxf(x, -15.f), 15.f);
  float e = __expf(2.f * x);
  return (e - 1.f) / (e + 1.f);
}
__device__ __forceinline__ unsigned short f2bf(float f) {
  unsigned u = __float_as_uint(f);
  u += 0x7FFFu + ((u >> 16) & 1u);
  return (unsigned short)(u >> 16);
}
__device__ __forceinline__ float bf2f(unsigned short s) {
  return __uint_as_float(((unsigned)s) << 16);
}

// ---------------------------------------------------------------- gather ----
__global__ void k_gather(const int* __restrict__ concepts, const float* __restrict__ emb,
                         float* __restrict__ X) {
  int m = blockIdx.x;                       // m = s*16 + b
  int tok = concepts[m];
  const float4* src = reinterpret_cast<const float4*>(emb + (size_t)tok * E_);
  float4* dst = reinterpret_cast<float4*>(X + (size_t)m * E_);
  for (int i = threadIdx.x; i < E_ / 4; i += blockDim.x) dst[i] = src[i];
}

// ------------------------------------------------------------------ GEMM ----
// C[m][n] = sum_k A[m][k] * W[n][k] + bias[n], row-major C[m*N + n]
__global__ __launch_bounds__(256) void k_gemm(const float* __restrict__ A,
                                              const float* __restrict__ W,
                                              const float* __restrict__ bias,
                                              float* __restrict__ C,
                                              int M, int N, int K) {
  __shared__ __align__(16) float As[16][132];
  __shared__ __align__(16) float Ws[16][132];
  const int bm = blockIdx.x * 128, bn = blockIdx.y * 128;
  const int tid = threadIdx.x;
  const int tm = (tid >> 4) * 8, tn = (tid & 15) * 8;
  float acc[8][8];
#pragma unroll
  for (int i = 0; i < 8; i++)
#pragma unroll
    for (int j = 0; j < 8; j++) acc[i][j] = 0.f;

  const int lr = tid >> 1, lk = (tid & 1) * 8;
  for (int k0 = 0; k0 < K; k0 += 16) {
    float4 a0 = *(const float4*)(A + (size_t)(bm + lr) * K + k0 + lk);
    float4 a1 = *(const float4*)(A + (size_t)(bm + lr) * K + k0 + lk + 4);
    float4 w0 = *(const float4*)(W + (size_t)(bn + lr) * K + k0 + lk);
    float4 w1 = *(const float4*)(W + (size_t)(bn + lr) * K + k0 + lk + 4);
    As[lk + 0][lr] = a0.x; As[lk + 1][lr] = a0.y; As[lk + 2][lr] = a0.z; As[lk + 3][lr] = a0.w;
    As[lk + 4][lr] = a1.x; As[lk + 5][lr] = a1.y; As[lk + 6][lr] = a1.z; As[lk + 7][lr] = a1.w;
    Ws[lk + 0][lr] = w0.x; Ws[lk + 1][lr] = w0.y; Ws[lk + 2][lr] = w0.z; Ws[lk + 3][lr] = w0.w;
    Ws[lk + 4][lr] = w1.x; Ws[lk + 5][lr] = w1.y; Ws[lk + 6][lr] = w1.z; Ws[lk + 7][lr] = w1.w;
    __syncthreads();
#pragma unroll
    for (int k = 0; k < 16; k++) {
      float4 av0 = *(const float4*)&As[k][tm];
      float4 av1 = *(const float4*)&As[k][tm + 4];
      float4 wv0 = *(const float4*)&Ws[k][tn];
      float4 wv1 = *(const float4*)&Ws[k][tn + 4];
      float a[8] = {av0.x, av0.y, av0.z, av0.w, av1.x, av1.y, av1.z, av1.w};
      float w[8] = {wv0.x, wv0.y, wv0.z, wv0.w, wv1.x, wv1.y, wv1.z, wv1.w};
#pragma unroll
      for (int i = 0; i < 8; i++)
#pragma unroll
        for (int j = 0; j < 8; j++) acc[i][j] += a[i] * w[j];
    }
    __syncthreads();
  }

  float bv[8];
#pragma unroll
  for (int j = 0; j < 8; j++) bv[j] = bias ? bias[bn + tn + j] : 0.f;
#pragma unroll
  for (int i = 0; i < 8; i++) {
    float4 v0 = make_float4(acc[i][0] + bv[0], acc[i][1] + bv[1], acc[i][2] + bv[2], acc[i][3] + bv[3]);
    float4 v1 = make_float4(acc[i][4] + bv[4], acc[i][5] + bv[5], acc[i][6] + bv[6], acc[i][7] + bv[7]);
    *(float4*)(C + (size_t)(bm + tm + i) * N + bn + tn) = v0;
    *(float4*)(C + (size_t)(bm + tm + i) * N + bn + tn + 4) = v1;
  }
}

// ------------------------------------------------------------- LSTM layer ----
// Grid: 8 WGs = dir(2) x w(4), 1024 threads (16 waves). WG (d,w) owns units
// [w*64, w*64+64) = gate rows q*256 + w*64 + [0,64). Wave ww = (q=ww>>2,
// t4=ww&3) computes tile rows q*256+w*64+t4*16+[0,16) x all 16 batches.
// A = whh rows split bf16 hi/lo in VGPRs (one-time). B = h_prev from Hbuf
// u64 {stamp,packed} entries (stage: 4 loads/lane, stamp-retry), via LDS.
// Gin: [m][2048] row-major; Hout: [m][512]; Hbuf: [d][parity][b][unit] u64.
__global__ __launch_bounds__(1024) void k_lstm(const float* __restrict__ Gin,
                                               const float* __restrict__ whh,
                                               float* __restrict__ Hout,
                                               unsigned long long* __restrict__ Hbuf) {
  const int d = blockIdx.x >> 2;
  const int w = blockIdx.x & 3;
  const int tid = threadIdx.x;
  const int ww = tid >> 6;         // wave
  const int q = ww >> 2;           // gate (i,f,g,o)
  const int t4 = ww & 3;           // unit subtile within WG
  const int lane = tid & 63;
  const int bcol = lane & 15;      // MFMA: A row-in-tile / C col (batch for B/C)
  const int quad = lane >> 4;      // MFMA k-group / C row group
  const int u_e = tid & 63;        // epilogue: unit within WG (0..63)
  const int b_e = tid >> 6;        // epilogue: batch (0..15)
  __shared__ unsigned int hL[16 * 260];           // packed h: [b]*260 + [k]
  __shared__ __align__(16) float Lg[4][16][68];   // [gate][batch][unit(+pad)]

  // ---- one-time: A fragments (whh rows) into VGPRs, split bf16 hi/lo ----
  unsigned int Am[8][4], Ar[8][4];
  {
    const int row = (d << 10) + (q << 8) + (w << 6) + (t4 << 4) + bcol;
    const float* wrow = whh + (size_t)row * 256;
#pragma unroll
    for (int s = 0; s < 8; ++s) {
      float wv[8];
      *(float4*)&wv[0] = *(const float4*)(wrow + s * 32 + quad * 8);
      *(float4*)&wv[4] = *(const float4*)(wrow + s * 32 + quad * 8 + 4);
#pragma unroll
      for (int j = 0; j < 4; ++j) {
        unsigned short m0 = f2bf(wv[2 * j]), m1 = f2bf(wv[2 * j + 1]);
        unsigned short r0 = f2bf(wv[2 * j] - bf2f(m0));
        unsigned short r1 = f2bf(wv[2 * j + 1] - bf2f(m1));
        Am[s][j] = (unsigned)m0 | ((unsigned)m1 << 16);
        Ar[s][j] = (unsigned)r0 | ((unsigned)r1 << 16);
      }
    }
  }

  float c_reg = 0.f;
  for (int it = 0; it < 256; ++it) {
    const int step = d ? (255 - it) : it;

    // ---- Gin prefetch: wave=batch b_e, lane=unit u_e -> coalesced 256B ----
    float gin[4];
#pragma unroll
    for (int qq = 0; qq < 4; ++qq)
      gin[qq] = Gin[((size_t)((step << 4) + b_e) << 11) + (d << 10) + (qq << 8) + (w << 6) + u_e];

    // ---- stage h_prev: 4 u64 loads/lane, stamp-retry, write LDS ----
    if (it > 0) {
      const unsigned long long* src = Hbuf + ((size_t)((d << 1) + ((it - 1) & 1)) << 12);
      const unsigned int want = (unsigned int)it;
      unsigned long long v[4];
#pragma unroll
      for (int c = 0; c < 4; ++c)
        v[c] = __hip_atomic_load(src + (c << 10) + tid, __ATOMIC_RELAXED,
                                 __HIP_MEMORY_SCOPE_AGENT);
      for (;;) {
        unsigned int badm = 0;
#pragma unroll
        for (int c = 0; c < 4; ++c)
          badm |= ((unsigned int)(v[c] >> 32) != want) ? (1u << c) : 0u;
        if (__ballot(badm != 0) == 0ull) break;
#pragma unroll
        for (int c = 0; c < 4; ++c)
          if (badm & (1u << c))
            v[c] = __hip_atomic_load(src + (c << 10) + tid, __ATOMIC_RELAXED,
                                     __HIP_MEMORY_SCOPE_AGENT);
      }
#pragma unroll
      for (int c = 0; c < 4; ++c) {
        int e_b = (c << 2) + (tid >> 8);           // entry e = c*1024+tid = b*256+k
        int e_k = tid & 255;
        hL[e_b * 260 + e_k] = (unsigned int)v[c];
      }
    }
    __syncthreads();

    // ---- B fragments from LDS, 3-product split MFMA ----
    f32x4 acc0 = {0.f, 0.f, 0.f, 0.f}, acc1 = acc0, acc2 = acc0;
    if (it > 0) {
#pragma unroll
      for (int s = 0; s < 8; ++s) {
        const unsigned int* p = &hL[bcol * 260 + (s << 5) + (quad << 3)];
        uint4 p0 = *(const uint4*)p;
        uint4 p1 = *(const uint4*)(p + 4);
        union { unsigned int u[4]; short8 v; } Bm, Br, Amu, Aru;
        Bm.u[0] = __builtin_amdgcn_perm(p0.y, p0.x, 0x05040100u);
        Br.u[0] = __builtin_amdgcn_perm(p0.y, p0.x, 0x07060302u);
        Bm.u[1] = __builtin_amdgcn_perm(p0.w, p0.z, 0x05040100u);
        Br.u[1] = __builtin_amdgcn_perm(p0.w, p0.z, 0x07060302u);
        Bm.u[2] = __builtin_amdgcn_perm(p1.y, p1.x, 0x05040100u);
        Br.u[2] = __builtin_amdgcn_perm(p1.y, p1.x, 0x07060302u);
        Bm.u[3] = __builtin_amdgcn_perm(p1.w, p1.z, 0x05040100u);
        Br.u[3] = __builtin_amdgcn_perm(p1.w, p1.z, 0x07060302u);
#pragma unroll
        for (int j = 0; j < 4; ++j) { Amu.u[j] = Am[s][j]; Aru.u[j] = Ar[s][j]; }
        acc0 = __builtin_amdgcn_mfma_f32_16x16x32_bf16(Amu.v, Bm.v, acc0, 0, 0, 0);
        acc1 = __builtin_amdgcn_mfma_f32_16x16x32_bf16(Amu.v, Br.v, acc1, 0, 0, 0);
        acc2 = __builtin_amdgcn_mfma_f32_16x16x32_bf16(Aru.v, Bm.v, acc2, 0, 0, 0);
      }
    }
    // ---- gate tile -> LDS (C layout: col=bcol=batch, row=quad*4+i=unit) ----
    {
      f32x4 t = acc0 + acc1 + acc2;
      *(float4*)&Lg[q][bcol][(t4 << 4) + (quad << 2)] = make_float4(t[0], t[1], t[2], t[3]);
    }
    __syncthreads();

    // ---- nonlinearity + state update; fire-and-forget publish ----
    {
      float gi = Lg[0][b_e][u_e] + gin[0];
      float gf = Lg[1][b_e][u_e] + gin[1];
      float gg = Lg[2][b_e][u_e] + gin[2];
      float go = Lg[3][b_e][u_e] + gin[3];
      float ct = sigm(gf) * c_reg + sigm(gi) * tanh_fast(gg);
      c_reg = ct;
      float h = sigm(go) * tanh_fast(ct);
      unsigned short hm = f2bf(h);
      unsigned short hr = f2bf(h - bf2f(hm));
      unsigned long long hp = ((unsigned long long)(unsigned int)(it + 1) << 32) |
                              (unsigned long long)(((unsigned)hr << 16) | (unsigned)hm);
      int unit = (w << 6) + u_e;
      __hip_atomic_store(Hbuf + ((size_t)((d << 1) + (it & 1)) << 12) + (b_e << 8) + unit,
                         hp, __ATOMIC_RELAXED, __HIP_MEMORY_SCOPE_AGENT);
      Hout[(size_t)((step << 4) + b_e) * 512 + (d << 8) + unit] = h;
    }
    // no drain barrier: consumers validate stamps themselves.
  }
}

// ------------------------------------------------------------- attention ----
// scores[b][i][j] = sum_h va[h]*tanh(P[i*16+b][h] + Cc[j*16+b][h])
// out[0 .. 1M) = scores; out[1M .. 2M) = predictions (sigmoid>=0.5 <=> x>=0)
__global__ __launch_bounds__(256) void k_attn(const float* __restrict__ P,
                                              const float* __restrict__ Cc,
                                              const float* __restrict__ va,
                                              float* __restrict__ out) {
  const int b = blockIdx.x & 15, i = blockIdx.x >> 4;
  __shared__ float pv[128], vv[128];
  const int t = threadIdx.x;
  if (t < 128) {
    pv[t] = P[(size_t)((i << 4) + b) * 128 + t];
    vv[t] = va[t];
  }
  __syncthreads();
  const float4* c4 = reinterpret_cast<const float4*>(Cc + (size_t)((t << 4) + b) * 128);
  float acc = 0.f;
#pragma unroll 8
  for (int hh = 0; hh < 32; ++hh) {
    float4 cv = c4[hh];
    int h = hh << 2;
    acc += vv[h]     * tanh_fast(pv[h]     + cv.x);
    acc += vv[h + 1] * tanh_fast(pv[h + 1] + cv.y);
    acc += vv[h + 2] * tanh_fast(pv[h + 2] + cv.z);
    acc += vv[h + 3] * tanh_fast(pv[h + 3] + cv.w);
  }
  size_t o = ((size_t)b << 16) + ((size_t)i << 8) + (size_t)t;
  out[o] = acc;
  out[(1u << 20) + o] = (acc >= 0.f) ? 1.f : 0.f;
}

// --------------------------------------------------------------- launch ----
extern "C" void kernel_launch(void* const* d_in, const int* in_sizes, int n_in,
                              void* d_out, int out_size, void* d_ws, size_t ws_size,
                              hipStream_t stream) {
  const int*   concepts = (const int*)d_in[0];
  // d_in[1] = concepts_lengths (all == S, unused)
  const float* emb  = (const float*)d_in[2];
  const float* w_ih = (const float*)d_in[3];   // [2][2][1024][512]
  const float* w_hh = (const float*)d_in[4];   // [2][2][1024][256]
  const float* bias = (const float*)d_in[5];   // [2][2][1024]
  const float* Ua   = (const float*)d_in[6];   // [128][512]
  const float* Wa   = (const float*)d_in[7];   // [128][512]
  const float* va   = (const float*)d_in[8];   // [1][128]
  float* out = (float*)d_out;
  float* ws  = (float*)d_ws;

  constexpr size_t OFF_X   = 0;
  constexpr size_t OFF_G   = OFF_X  + (size_t)M_ * E_;
  constexpr size_t OFF_H0  = OFF_G  + (size_t)M_ * 2048;
  constexpr size_t OFF_H1  = OFF_H0 + (size_t)M_ * 512;
  constexpr size_t OFF_P   = OFF_H1 + (size_t)M_ * 512;
  constexpr size_t OFF_C   = OFF_P  + (size_t)M_ * HM_;
  constexpr size_t OFF_HB  = OFF_C  + (size_t)M_ * HM_;   // u64[2 layers][2d][2par][4096]

  float* X  = ws + OFF_X;
  float* G  = ws + OFF_G;
  float* H0 = ws + OFF_H0;
  float* H1 = ws + OFF_H1;
  float* Pm = ws + OFF_P;
  float* Cm = ws + OFF_C;
  unsigned long long* Hb0 = (unsigned long long*)(ws + OFF_HB);
  unsigned long long* Hb1 = Hb0 + 2 * 2 * 4096;

  k_gather<<<M_, 128, 0, stream>>>(concepts, emb, X);

  // layer 0
  k_gemm<<<dim3(32, 16), 256, 0, stream>>>(X, w_ih, bias, G, M_, 2048, 512);
  k_lstm<<<8, 1024, 0, stream>>>(G, w_hh, H0, Hb0);

  // layer 1
  k_gemm<<<dim3(32, 16), 256, 0, stream>>>(H0, w_ih + (size_t)2048 * 512, bias + 2048,
                                           G, M_, 2048, 512);
  k_lstm<<<8, 1024, 0, stream>>>(G, w_hh + (size_t)2048 * 256, H1, Hb1);

  // attention projections
  k_gemm<<<dim3(32, 1), 256, 0, stream>>>(H1, Ua, nullptr, Pm, M_, HM_, 512);
  k_gemm<<<dim3(32, 1), 256, 0, stream>>>(H1, Wa, nullptr, Cm, M_, HM_, 512);

  // fused pairwise scores + predictions
  k_attn<<<M_, 256, 0, stream>>>(Pm, Cm, va, out);
}